// Round 1
// baseline (1526.092 us; speedup 1.0000x reference)
//
#include <hip/hip_runtime.h>
#include <hip/hip_fp16.h>

#define TT   2048
#define BB   64
#define II   16
#define HH   8
#define HIDN 64
#define GG   256   // 4*HIDN

typedef _Float16 h2 __attribute__((ext_vector_type(2)));
typedef _Float16 h8 __attribute__((ext_vector_type(8)));

__device__ __forceinline__ float fdot2(h2 a, h2 b, float c) {
    return __builtin_amdgcn_fdot2(a, b, c, false);
}

__device__ __forceinline__ float fast_sigmoid(float z) {
    return __builtin_amdgcn_rcpf(1.0f + __expf(-z));
}
__device__ __forceinline__ float fast_tanh(float z) {
    float s = __builtin_amdgcn_rcpf(1.0f + __expf(-2.0f * z));
    return 2.0f * s - 1.0f;
}

// ---------------- x -> f16 conversion (one-time, trivial) ----------------
__global__ void cvt_x_kernel(const float* __restrict__ x, _Float16* __restrict__ xh, int n4) {
    int i = blockIdx.x * blockDim.x + threadIdx.x;
    if (i < n4) {
        float4 v = ((const float4*)x)[i];
        h2 a = { (_Float16)v.x, (_Float16)v.y };
        h2 b = { (_Float16)v.z, (_Float16)v.w };
        ((h2*)xh)[2 * i]     = a;
        ((h2*)xh)[2 * i + 1] = b;
    }
}

// ---------------- main recurrent kernel ----------------
// grid = BB*HH blocks (one independent LSTM chain each), 256 threads.
// thread j: gate row j of this (b,head). wave w == gate w (i,f,g,o) -> uniform act branch.
template <int STAGE, bool XF16>
__global__ __launch_bounds__(256)
void lstm_main(const float* __restrict__ x,
               const _Float16* __restrict__ xh,
               const float* __restrict__ Wih,
               const float* __restrict__ Whh,
               const float* __restrict__ bih,
               const float* __restrict__ bhh,
               const float* __restrict__ Wlin,
               const float* __restrict__ blin,
               float* __restrict__ out,        // (T,B,H)
               float* __restrict__ lstm_out,   // (T,B,HIDN)  (used by STAGE==2)
               float* __restrict__ stage_f32,  // (T,B,H,HIDN)
               _Float16* __restrict__ stage_f16)
{
    const int tid = threadIdx.x;
    const int b   = blockIdx.x & (BB - 1);
    const int hd  = blockIdx.x >> 6;
    const int wv  = tid >> 6;

    // ---- weights resident in VGPRs, converted to f16 pairs ----
    h2 wih[II / 2];
    {
        const float4* p = (const float4*)(Wih + (size_t)(hd * GG + tid) * II);
#pragma unroll
        for (int q = 0; q < II / 4; ++q) {
            float4 v = p[q];
            wih[2 * q]     = h2{ (_Float16)v.x, (_Float16)v.y };
            wih[2 * q + 1] = h2{ (_Float16)v.z, (_Float16)v.w };
        }
    }
    h2 whh[HIDN / 2];
    {
        const float4* p = (const float4*)(Whh + (size_t)(hd * GG + tid) * HIDN);
#pragma unroll
        for (int q = 0; q < HIDN / 4; ++q) {
            float4 v = p[q];
            whh[2 * q]     = h2{ (_Float16)v.x, (_Float16)v.y };
            whh[2 * q + 1] = h2{ (_Float16)v.z, (_Float16)v.w };
        }
    }
    const float bias = bih[hd * GG + tid] + bhh[hd * GG + tid];

    float wl = 0.0f;
    if (tid < HIDN) wl = Wlin[hd * HIDN + tid];
    const float bl = blin[hd];

    __shared__ __align__(16) _Float16 hbuf[HIDN];  // current h (f16) for dot2
    __shared__ float gsm[GG];                      // activated gates

    float c = 0.0f;
    if (tid < HIDN) hbuf[tid] = (_Float16)0.0f;
    __syncthreads();

    const _Float16* xhp = xh + b * II;
    const float*    xfp = x + b * II;

    h2 xv[II / 2];
    auto load_x = [&](int t, h2* dst) {
        if (XF16) {
            const h8* p = (const h8*)(xhp + (size_t)t * BB * II);
            union { h8 v; h2 p2[4]; } u0, u1;
            u0.v = p[0];
            u1.v = p[1];
#pragma unroll
            for (int i = 0; i < 4; ++i) { dst[i] = u0.p2[i]; dst[4 + i] = u1.p2[i]; }
        } else {
            const float4* p = (const float4*)(xfp + (size_t)t * BB * II);
#pragma unroll
            for (int q = 0; q < 4; ++q) {
                float4 v = p[q];
                dst[2 * q]     = h2{ (_Float16)v.x, (_Float16)v.y };
                dst[2 * q + 1] = h2{ (_Float16)v.z, (_Float16)v.w };
            }
        }
    };
    load_x(0, xv);

    for (int t = 0; t < TT; ++t) {
        // prefetch next x row (overlaps the whole step)
        h2 xnext[II / 2];
        if (t + 1 < TT) load_x(t + 1, xnext);

        // z = bias + W_hh . h + W_ih . x   (4 independent accumulators for ILP)
        float a0 = bias, a1 = 0.0f, a2 = 0.0f, a3 = 0.0f;
#pragma unroll
        for (int q = 0; q < HIDN / 8; ++q) {  // 8 x ds_read_b128 broadcast
            union { h8 v; h2 p2[4]; } u;
            u.v = ((const h8*)hbuf)[q];
            a0 = fdot2(whh[4 * q + 0], u.p2[0], a0);
            a1 = fdot2(whh[4 * q + 1], u.p2[1], a1);
            a2 = fdot2(whh[4 * q + 2], u.p2[2], a2);
            a3 = fdot2(whh[4 * q + 3], u.p2[3], a3);
        }
#pragma unroll
        for (int i = 0; i < II / 2; i += 4) {
            a0 = fdot2(wih[i + 0], xv[i + 0], a0);
            a1 = fdot2(wih[i + 1], xv[i + 1], a1);
            a2 = fdot2(wih[i + 2], xv[i + 2], a2);
            a3 = fdot2(wih[i + 3], xv[i + 3], a3);
        }
        float z = (a0 + a1) + (a2 + a3);

        // activation: wave 2 == gate g -> tanh; others sigmoid (wave-uniform branch)
        float act = (wv == 2) ? fast_tanh(z) : fast_sigmoid(z);
        gsm[tid] = act;
        __syncthreads();

        if (tid < HIDN) {  // wave 0: state update + outputs
            float gi = gsm[tid];
            float gf = gsm[HIDN + tid];
            float gg = gsm[2 * HIDN + tid];
            float go = gsm[3 * HIDN + tid];
            c = gf * c + gi * gg;
            float h = go * fast_tanh(c);
            hbuf[tid] = (_Float16)h;

            if (STAGE == 0) {
                stage_f32[(((size_t)t * BB + b) * HH + hd) * HIDN + tid] = h;
            } else if (STAGE == 1) {
                stage_f16[(((size_t)t * BB + b) * HH + hd) * HIDN + tid] = (_Float16)h;
            } else {
                atomicAdd(&lstm_out[((size_t)t * BB + b) * HIDN + tid], h);
            }

            // out[t,b,hd] = dot(h, W_lin) + b_lin : wave-wide shuffle reduce
            float p = h * wl;
#pragma unroll
            for (int off = 32; off > 0; off >>= 1) p += __shfl_down(p, off);
            if (tid == 0) out[((size_t)t * BB + b) * HH + hd] = p + bl;
        }
        __syncthreads();

#pragma unroll
        for (int i = 0; i < II / 2; ++i) xv[i] = xnext[i];
    }
}

// ---------------- head-sum reduction (memory-bound) ----------------
template <bool F16>
__global__ void reduce_heads(const float* __restrict__ sf32,
                             const _Float16* __restrict__ sf16,
                             float* __restrict__ lstm_out)
{
    size_t j = (size_t)blockIdx.x * blockDim.x + threadIdx.x;  // 0 .. T*B*HIDN
    int k = (int)(j & (HIDN - 1));
    size_t tb = j >> 6;
    size_t base = tb * HH * HIDN + k;
    float s = 0.0f;
#pragma unroll
    for (int h = 0; h < HH; ++h)
        s += F16 ? (float)sf16[base + h * HIDN] : sf32[base + h * HIDN];
    lstm_out[j] = s;
}

extern "C" void kernel_launch(void* const* d_in, const int* in_sizes, int n_in,
                              void* d_out, int out_size, void* d_ws, size_t ws_size,
                              hipStream_t stream)
{
    const float* x    = (const float*)d_in[0];
    const float* Wih  = (const float*)d_in[1];
    const float* Whh  = (const float*)d_in[2];
    const float* bih  = (const float*)d_in[3];
    const float* bhh  = (const float*)d_in[4];
    const float* Wlin = (const float*)d_in[5];
    const float* blin = (const float*)d_in[6];

    float* out  = (float*)d_out;
    float* lstm = out + (size_t)TT * BB * HH;

    const size_t xbytes = (size_t)TT * BB * II * 2;          // 4 MB
    const size_t slab32 = (size_t)TT * BB * HH * HIDN * 4;   // 268 MB
    const size_t slab16 = slab32 / 2;                        // 134 MB

    const bool xf16 = ws_size >= xbytes;
    _Float16* xh = (_Float16*)d_ws;
    char* slabp  = (char*)d_ws + (xf16 ? xbytes : 0);
    size_t avail = ws_size - (xf16 ? xbytes : 0);
    const int mode = (avail >= slab32) ? 0 : (avail >= slab16 ? 1 : 2);

    if (xf16) {
        int n4 = TT * BB * II / 4;
        cvt_x_kernel<<<(n4 + 255) / 256, 256, 0, stream>>>(x, xh, n4);
    }
    if (mode == 2) {
        hipMemsetAsync(lstm, 0, (size_t)TT * BB * HIDN * 4, stream);
    }

    dim3 grid(BB * HH), block(256);
    float*    sf = (float*)slabp;
    _Float16* sh = (_Float16*)slabp;

#define LAUNCH_MAIN(M, XF) \
    lstm_main<M, XF><<<grid, block, 0, stream>>>(x, xh, Wih, Whh, bih, bhh, Wlin, blin, out, lstm, sf, sh)

    if (xf16) {
        if (mode == 0)      LAUNCH_MAIN(0, true);
        else if (mode == 1) LAUNCH_MAIN(1, true);
        else                LAUNCH_MAIN(2, true);
    } else {
        if (mode == 0)      LAUNCH_MAIN(0, false);
        else if (mode == 1) LAUNCH_MAIN(1, false);
        else                LAUNCH_MAIN(2, false);
    }
#undef LAUNCH_MAIN

    if (mode == 0) {
        reduce_heads<false><<<(TT * BB * HIDN) / 256, 256, 0, stream>>>(sf, nullptr, lstm);
    } else if (mode == 1) {
        reduce_heads<true><<<(TT * BB * HIDN) / 256, 256, 0, stream>>>(nullptr, sh, lstm);
    }
}

// Round 2
// 1396.581 us; speedup vs baseline: 1.0927x; 1.0927x over previous
//
#include <hip/hip_runtime.h>
#include <hip/hip_fp16.h>

#define TT   2048
#define BB   64
#define II   16
#define HH   8
#define HIDN 64
#define GG   256   // 4*HIDN

typedef _Float16 h2 __attribute__((ext_vector_type(2)));
typedef _Float16 h8 __attribute__((ext_vector_type(8)));

__device__ __forceinline__ float fdot2(h2 a, h2 b, float c) {
    return __builtin_amdgcn_fdot2(a, b, c, false);
}

// ---------------- x -> f16 conversion (one-time, trivial) ----------------
__global__ void cvt_x_kernel(const float* __restrict__ x, _Float16* __restrict__ xh, int n4) {
    int i = blockIdx.x * blockDim.x + threadIdx.x;
    if (i < n4) {
        float4 v = ((const float4*)x)[i];
        ((h2*)xh)[2 * i]     = h2{ (_Float16)v.x, (_Float16)v.y };
        ((h2*)xh)[2 * i + 1] = h2{ (_Float16)v.z, (_Float16)v.w };
    }
}

// ---------------- main recurrent kernel ----------------
// grid = BB*HH blocks (one independent LSTM chain each), 256 threads.
// thread tid: gate (tid&3) of hidden unit (tid>>2) -> weight row gate*64+unit.
// All 4 gates of a unit sit in adjacent lanes of ONE wave -> gate exchange is
// 4 shuffles; c/h update is computed redundantly by all 4 lanes (no serial
// tail). Only h round-trips LDS (double-buffered, ONE barrier per step).
template <int STAGE, bool XF16>
__global__ __launch_bounds__(256)
void lstm_main(const float* __restrict__ x,
               const _Float16* __restrict__ xh,
               const float* __restrict__ Wih,
               const float* __restrict__ Whh,
               const float* __restrict__ bih,
               const float* __restrict__ bhh,
               const float* __restrict__ Wlin,
               const float* __restrict__ blin,
               float* __restrict__ out,        // (T,B,H)
               float* __restrict__ lstm_out,   // (T,B,HIDN)  (STAGE==2 atomics)
               float* __restrict__ stage_f32,  // (T,B,H,HIDN)
               _Float16* __restrict__ stage_f16)
{
    const int tid  = threadIdx.x;
    const int b    = blockIdx.x & (BB - 1);
    const int hd   = blockIdx.x >> 6;
    const int gate = tid & 3;
    const int unit = tid >> 2;
    const int wv   = tid >> 6;
    const int lbase = (tid & 63) & ~3;   // wave-local lane of this unit's gate 0
    const int r    = gate * HIDN + unit; // PyTorch gate-major row index

    // ---- weights resident in VGPRs, converted to f16 pairs ----
    h2 wih[II / 2];
    {
        const float4* p = (const float4*)(Wih + (size_t)(hd * GG + r) * II);
#pragma unroll
        for (int q = 0; q < II / 4; ++q) {
            float4 v = p[q];
            wih[2 * q]     = h2{ (_Float16)v.x, (_Float16)v.y };
            wih[2 * q + 1] = h2{ (_Float16)v.z, (_Float16)v.w };
        }
    }
    h2 whh[HIDN / 2];
    {
        const float4* p = (const float4*)(Whh + (size_t)(hd * GG + r) * HIDN);
#pragma unroll
        for (int q = 0; q < HIDN / 4; ++q) {
            float4 v = p[q];
            whh[2 * q]     = h2{ (_Float16)v.x, (_Float16)v.y };
            whh[2 * q + 1] = h2{ (_Float16)v.z, (_Float16)v.w };
        }
    }
    const float bias = bih[hd * GG + r] + bhh[hd * GG + r];
    const float wl   = Wlin[hd * HIDN + unit];
    const float bl   = blin[hd];

    // activation constants: tanh(z) = 2*sigmoid(2z)-1 -> one exp path, no divergence
    const float negm = (gate == 2) ? -2.0f : -1.0f;
    const float sc   = (gate == 2) ?  2.0f :  1.0f;
    const float ofs  = (gate == 2) ? -1.0f :  0.0f;

    __shared__ __align__(16) _Float16 hbuf[2][HIDN];  // double-buffered h (f16)
    __shared__ __align__(16) float    obuf[2][4];     // per-wave W_lin partials

    if (tid < HIDN) hbuf[0][tid] = (_Float16)0.0f;
    __syncthreads();

    float c = 0.0f;

    const _Float16* xhp = xh + b * II;
    const float*    xfp = x + b * II;
    h2 xv[II / 2];
    auto load_x = [&](int t, h2* dst) {
        if (XF16) {
            const h8* p = (const h8*)(xhp + (size_t)t * BB * II);
            union { h8 v; h2 p2[4]; } u0, u1;
            u0.v = p[0];
            u1.v = p[1];
#pragma unroll
            for (int i = 0; i < 4; ++i) { dst[i] = u0.p2[i]; dst[4 + i] = u1.p2[i]; }
        } else {
            const float4* p = (const float4*)(xfp + (size_t)t * BB * II);
#pragma unroll
            for (int q = 0; q < 4; ++q) {
                float4 v = p[q];
                dst[2 * q]     = h2{ (_Float16)v.x, (_Float16)v.y };
                dst[2 * q + 1] = h2{ (_Float16)v.z, (_Float16)v.w };
            }
        }
    };
    load_x(0, xv);

    for (int t = 0; t < TT; ++t) {
        // deferred out-write: obuf slot t&1 was filled at step t-2 (barrier-ordered)
        if (t >= 2 && tid == 0) {
            float4 o4 = *(const float4*)obuf[t & 1];
            out[((size_t)(t - 2) * BB + b) * HH + hd] = o4.x + o4.y + o4.z + o4.w + bl;
        }

        h2 xnext[II / 2];
        if (t + 1 < TT) load_x(t + 1, xnext);

        // z = bias + W_hh . h + W_ih . x   (4 accumulators for ILP)
        float a0 = bias, a1 = 0.0f, a2 = 0.0f, a3 = 0.0f;
        const h8* hb = (const h8*)hbuf[t & 1];
#pragma unroll
        for (int q = 0; q < HIDN / 8; ++q) {  // 8 x ds_read_b128 broadcast
            union { h8 v; h2 p2[4]; } u;
            u.v = hb[q];
            a0 = fdot2(whh[4 * q + 0], u.p2[0], a0);
            a1 = fdot2(whh[4 * q + 1], u.p2[1], a1);
            a2 = fdot2(whh[4 * q + 2], u.p2[2], a2);
            a3 = fdot2(whh[4 * q + 3], u.p2[3], a3);
        }
#pragma unroll
        for (int i = 0; i < II / 2; i += 4) {
            a0 = fdot2(wih[i + 0], xv[i + 0], a0);
            a1 = fdot2(wih[i + 1], xv[i + 1], a1);
            a2 = fdot2(wih[i + 2], xv[i + 2], a2);
            a3 = fdot2(wih[i + 3], xv[i + 3], a3);
        }
        float z = (a0 + a1) + (a2 + a3);

        // one exp+rcp per lane, no divergence
        float e   = __expf(negm * z);
        float s   = __builtin_amdgcn_rcpf(1.0f + e);
        float act = fmaf(s, sc, ofs);

        // gather the 4 gates of my unit from adjacent lanes
        float gi = __shfl(act, lbase + 0);
        float gf = __shfl(act, lbase + 1);
        float gg = __shfl(act, lbase + 2);
        float go = __shfl(act, lbase + 3);

        c = fmaf(gf, c, gi * gg);
        float e2 = __expf(-2.0f * c);
        float th = fmaf(2.0f, __builtin_amdgcn_rcpf(1.0f + e2), -1.0f);
        float h  = go * th;

        if (gate == 0) hbuf[(t + 1) & 1][unit] = (_Float16)h;
        __syncthreads();

        // post-barrier epilogue (registers only; overlaps next step's loads)
        if (gate == 0) {
            if (STAGE == 0) {
                stage_f32[(((size_t)t * BB + b) * HH + hd) * HIDN + unit] = h;
            } else if (STAGE == 1) {
                stage_f16[(((size_t)t * BB + b) * HH + hd) * HIDN + unit] = (_Float16)h;
            } else {
                atomicAdd(&lstm_out[((size_t)t * BB + b) * HIDN + unit], h);
            }
            float p = h * wl;
            p += __shfl_down(p, 32);
            p += __shfl_down(p, 16);
            p += __shfl_down(p, 8);
            p += __shfl_down(p, 4);
            if ((tid & 63) == 0) obuf[t & 1][wv] = p;  // read at step t+2
        }

#pragma unroll
        for (int i = 0; i < II / 2; ++i) xv[i] = xnext[i];
    }

    __syncthreads();
    if (tid == 0) {
        float4 oa = *(const float4*)obuf[0];
        float4 ob = *(const float4*)obuf[1];
        out[((size_t)(TT - 2) * BB + b) * HH + hd] = oa.x + oa.y + oa.z + oa.w + bl;
        out[((size_t)(TT - 1) * BB + b) * HH + hd] = ob.x + ob.y + ob.z + ob.w + bl;
    }
}

// ---------------- head-sum reduction (memory-bound) ----------------
template <bool F16>
__global__ void reduce_heads(const float* __restrict__ sf32,
                             const _Float16* __restrict__ sf16,
                             float* __restrict__ lstm_out)
{
    size_t j = (size_t)blockIdx.x * blockDim.x + threadIdx.x;  // 0 .. T*B*HIDN
    int k = (int)(j & (HIDN - 1));
    size_t tb = j >> 6;
    size_t base = tb * HH * HIDN + k;
    float s = 0.0f;
#pragma unroll
    for (int h = 0; h < HH; ++h)
        s += F16 ? (float)sf16[base + h * HIDN] : sf32[base + h * HIDN];
    lstm_out[j] = s;
}

extern "C" void kernel_launch(void* const* d_in, const int* in_sizes, int n_in,
                              void* d_out, int out_size, void* d_ws, size_t ws_size,
                              hipStream_t stream)
{
    const float* x    = (const float*)d_in[0];
    const float* Wih  = (const float*)d_in[1];
    const float* Whh  = (const float*)d_in[2];
    const float* bih  = (const float*)d_in[3];
    const float* bhh  = (const float*)d_in[4];
    const float* Wlin = (const float*)d_in[5];
    const float* blin = (const float*)d_in[6];

    float* out  = (float*)d_out;
    float* lstm = out + (size_t)TT * BB * HH;

    const size_t xbytes = (size_t)TT * BB * II * 2;          // 4 MB
    const size_t slab32 = (size_t)TT * BB * HH * HIDN * 4;   // 268 MB
    const size_t slab16 = slab32 / 2;                        // 134 MB

    const bool xf16 = ws_size >= xbytes;
    _Float16* xh = (_Float16*)d_ws;
    char* slabp  = (char*)d_ws + (xf16 ? xbytes : 0);
    size_t avail = ws_size - (xf16 ? xbytes : 0);
    const int mode = (avail >= slab32) ? 0 : (avail >= slab16 ? 1 : 2);

    if (xf16) {
        int n4 = TT * BB * II / 4;
        cvt_x_kernel<<<(n4 + 255) / 256, 256, 0, stream>>>(x, xh, n4);
    }
    if (mode == 2) {
        hipMemsetAsync(lstm, 0, (size_t)TT * BB * HIDN * 4, stream);
    }

    dim3 grid(BB * HH), block(256);
    float*    sf = (float*)slabp;
    _Float16* sh = (_Float16*)slabp;

#define LAUNCH_MAIN(M, XF) \
    lstm_main<M, XF><<<grid, block, 0, stream>>>(x, xh, Wih, Whh, bih, bhh, Wlin, blin, out, lstm, sf, sh)

    if (xf16) {
        if (mode == 0)      LAUNCH_MAIN(0, true);
        else if (mode == 1) LAUNCH_MAIN(1, true);
        else                LAUNCH_MAIN(2, true);
    } else {
        if (mode == 0)      LAUNCH_MAIN(0, false);
        else if (mode == 1) LAUNCH_MAIN(1, false);
        else                LAUNCH_MAIN(2, false);
    }
#undef LAUNCH_MAIN

    if (mode == 0) {
        reduce_heads<false><<<(TT * BB * HIDN) / 256, 256, 0, stream>>>(sf, nullptr, lstm);
    } else if (mode == 1) {
        reduce_heads<true><<<(TT * BB * HIDN) / 256, 256, 0, stream>>>(nullptr, sh, lstm);
    }
}